// Round 4
// baseline (233.201 us; speedup 1.0000x reference)
//
#include <hip/hip_runtime.h>

#define WINDOW 13
#define NTOT   53248      // 13*64*64 voxels per (b,c)
#define WPB    8          // windows per block
#define VT     104        // real voxels per block (8 windows)
#define VS     112        // staged voxels (7 MFMA col-tiles of 16)
#define WS     72         // bf16 row stride (pad 64->72: bank-quad step 1, conflict-free b128)
#define QKS    112        // qk fp32 row stride
#define VPS    132        // vpad bf16 row stride (8 win * 16 + 4 pad; 264B, 8B-aligned rows)

typedef float floatx4 __attribute__((ext_vector_type(4)));
typedef short shortx8 __attribute__((ext_vector_type(8)));

__device__ __forceinline__ unsigned short f2bf(float f) {
    union { float f; unsigned int u; } v; v.f = f;
    unsigned int u = v.u;
    unsigned int r = (u + 0x7fffu + ((u >> 16) & 1u)) >> 16;   // RNE
    return (unsigned short)r;
}

__device__ __forceinline__ unsigned int pk2(float a, float b) {
    return (unsigned int)f2bf(a) | ((unsigned int)f2bf(b) << 16);
}

// 512 threads/block, 52032 B LDS -> 3 blocks/CU = 24 waves/CU.
__global__ __launch_bounds__(512, 6)
void attn_win13_kernel(const float* __restrict__ x,
                       const float* __restrict__ wq, const float* __restrict__ bq,
                       const float* __restrict__ wk, const float* __restrict__ bk,
                       const float* __restrict__ wv, const float* __restrict__ bv,
                       float* __restrict__ out)
{
    // LDS: 16128 + 11520 + 320 + 16896 + 7168 = 52032 B -> 3 blocks/CU
    __shared__ __align__(16) unsigned short xT[VS * WS];    // bf16 x, transposed [vox][ch]
    __shared__ __align__(16) unsigned short wbf[80 * WS];   // bf16 weights (q 0..7, k 8..15, v 16..79); att fp32 aliases after P2
    __shared__ float ball[80];
    __shared__ __align__(16) unsigned short vpad[64 * VPS]; // bf16 v, [ch][w*16+j], j 13..15 zeroed
    __shared__ __align__(16) float qk[16 * QKS];            // fp32 q rows 0..7, k rows 8..15; attb aliases after P3a
    float* const att = (float*)wbf;                         // [w][i][j] fp32 = 5408 B <= 11520
    unsigned short* const attb = (unsigned short*)qk;       // [w][16][16] bf16 = 4096 B <= 7168

    const int tid = threadIdx.x;
    const int b   = blockIdx.y;
    const int v0  = blockIdx.x * VT;
    const size_t total = (size_t)512 * NTOT;   // 8*64 rows of x

    // ---- P1: staging, split across waves. ----
    if (tid < 224) {
        // Waves 0..3: x -> bf16 transposed LDS, 8 ch x 4 vox each, b128 writes.
        const int vq = tid >> 3, cg8 = tid & 7;
        const int c0 = cg8 * 8, vx = vq * 4;
        float xv[4][8];
#pragma unroll
        for (int i = 0; i < 8; ++i) {
            size_t idx = (size_t)(b * 64 + c0 + i) * NTOT + v0 + vx;
            if (idx > total - 4) idx = total - 4;   // clamp tail (garbage MFMA cols)
            const float4 t = *(const float4*)(x + idx);
            xv[0][i] = t.x; xv[1][i] = t.y; xv[2][i] = t.z; xv[3][i] = t.w;
        }
#pragma unroll
        for (int r = 0; r < 4; ++r) {
            uint4 pk;
            pk.x = pk2(xv[r][0], xv[r][1]);
            pk.y = pk2(xv[r][2], xv[r][3]);
            pk.z = pk2(xv[r][4], xv[r][5]);
            pk.w = pk2(xv[r][6], xv[r][7]);
            *(uint4*)(&xT[(vx + r) * WS + c0]) = pk;
        }
    } else if (tid >= 256) {
        // Waves 4..7: weights -> bf16 LDS, b128 writes.
        const int wf0 = tid - 256;
#pragma unroll
        for (int it = 0; it < 3; ++it) {
            const int wf = wf0 + (it << 8);
            if (wf < 640) {
                const int r = wf >> 3, cw = (wf & 7) * 8;
                const float* src = (r < 8)  ? (wq + r * 64 + cw)
                                 : (r < 16) ? (wk + (r - 8) * 64 + cw)
                                            : (wv + (r - 16) * 64 + cw);
                const float4 w0 = *(const float4*)src;
                const float4 w1 = *(const float4*)(src + 4);
                uint4 pk;
                pk.x = pk2(w0.x, w0.y); pk.y = pk2(w0.z, w0.w);
                pk.z = pk2(w1.x, w1.y); pk.w = pk2(w1.z, w1.w);
                *(uint4*)(&wbf[r * WS + cw]) = pk;
            }
        }
    }
    if (tid >= 432) {   // 80 bias loads
        const int t2 = tid - 432;
        ball[t2] = (t2 < 8) ? bq[t2] : (t2 < 16) ? bk[t2 - 8] : bv[t2 - 16];
    }
    // Zero vpad pad columns j=13..15 per window (NaN hygiene for P4's A-frag k=13..15).
    {
        const int r = tid >> 3, w = tid & 7;        // 64 rows x 8 windows = 512 = blockDim
        vpad[r * VPS + w * 16 + 13] = 0;
        *(unsigned int*)(&vpad[r * VPS + w * 16 + 14]) = 0u;
    }
    __syncthreads();

    // ---- P2: projection GEMM via MFMA. 5 m-tiles x 7 n-tiles, K=64 (2 mfma).
    // mt==0 (q/k): D rows = qk-ch, cols = vox -> fp32 qk (as before).
    // mt>=1 (v):  SWAPPED operands (A=xT, B=wbf) -> D rows = vox, cols = v-ch,
    //             thread holds 4 consecutive vox for one channel -> scatter bf16
    //             into vpad[ch][w*16+j]. Same LDS reads either way. ----
    {
        const int wid  = tid >> 6;
        const int lane = tid & 63;
        const int col  = lane & 15;
        const int g    = lane >> 4;          // k-chunk / row-quad
        for (int t = wid; t < 35; t += 8) {
            const int mt = t / 7, nt = t % 7;
            const shortx8 wa0 = *(const shortx8*)(&wbf[(mt * 16 + col) * WS + g * 8]);
            const shortx8 xa0 = *(const shortx8*)(&xT [(nt * 16 + col) * WS + g * 8]);
            const shortx8 wa1 = *(const shortx8*)(&wbf[(mt * 16 + col) * WS + 32 + g * 8]);
            const shortx8 xa1 = *(const shortx8*)(&xT [(nt * 16 + col) * WS + 32 + g * 8]);
            floatx4 acc = {0.f, 0.f, 0.f, 0.f};
            if (mt == 0) {                    // q/k: A=w, B=x -> rows=ch, cols=vox
                acc = __builtin_amdgcn_mfma_f32_16x16x32_bf16(wa0, xa0, acc, 0, 0, 0);
                acc = __builtin_amdgcn_mfma_f32_16x16x32_bf16(wa1, xa1, acc, 0, 0, 0);
                const int row0 = g * 4;
                const int vox  = nt * 16 + col;
                qk[(row0 + 0) * QKS + vox] = acc[0] + ball[row0 + 0];
                qk[(row0 + 1) * QKS + vox] = acc[1] + ball[row0 + 1];
                qk[(row0 + 2) * QKS + vox] = acc[2] + ball[row0 + 2];
                qk[(row0 + 3) * QKS + vox] = acc[3] + ball[row0 + 3];
            } else {                          // v: A=x, B=w -> rows=vox, cols=ch
                acc = __builtin_amdgcn_mfma_f32_16x16x32_bf16(xa0, wa0, acc, 0, 0, 0);
                acc = __builtin_amdgcn_mfma_f32_16x16x32_bf16(xa1, wa1, acc, 0, 0, 0);
                const int c_out = (mt - 1) * 16 + col;      // global v channel
                const float bias = ball[16 + c_out];
                int vox = nt * 16 + g * 4;
                int w = vox / 13, j = vox - w * 13;
#pragma unroll
                for (int r = 0; r < 4; ++r) {
                    if (vox + r < VT)
                        vpad[c_out * VPS + w * 16 + j] = f2bf(acc[r] + bias);
                    if (++j == 13) { j = 0; ++w; }
                }
            }
        }
    }
    __syncthreads();

    // ---- P3a: scores[w][i][j] = sum_o q[o][w13+i] * k[o][w13+j] (fp32, scalar). ----
    for (int f = tid; f < WPB * 169; f += 512) {
        const int w = f / 169, rem = f % 169;
        const int i = rem / 13, j = rem % 13;
        const float* qp = &qk[w * 13 + i];
        const float* kp = &qk[w * 13 + j];
        float s = 0.f;
#pragma unroll
        for (int o = 0; o < 8; ++o)
            s += qp[o * QKS] * kp[(8 + o) * QKS];
        att[f] = s;
    }
    __syncthreads();

    // ---- P3b: softmax over j; emit bf16 attb[w][i][0..15] (j>=13 zero). ----
    if (tid < WPB * WINDOW) {
        const int w = tid / 13, i = tid - w * 13;
        const float* row = att + w * 169 + i * 13;
        float m = row[0];
#pragma unroll
        for (int j = 1; j < 13; ++j) m = fmaxf(m, row[j]);
        float s0 = __expf(row[0] - m), s1 = __expf(row[1] - m), s2 = __expf(row[2] - m);
        float s3 = __expf(row[3] - m), s4 = __expf(row[4] - m), s5 = __expf(row[5] - m);
        float s6 = __expf(row[6] - m), s7 = __expf(row[7] - m), s8 = __expf(row[8] - m);
        float s9 = __expf(row[9] - m), sa = __expf(row[10] - m), sb = __expf(row[11] - m);
        float sc = __expf(row[12] - m);
        const float inv = 1.f / (s0+s1+s2+s3+s4+s5+s6+s7+s8+s9+sa+sb+sc);
        unsigned short* ab = attb + w * 256 + i * 16;
        uint4 lo, hi;
        lo.x = pk2(s0 * inv, s1 * inv); lo.y = pk2(s2 * inv, s3 * inv);
        lo.z = pk2(s4 * inv, s5 * inv); lo.w = pk2(s6 * inv, s7 * inv);
        hi.x = pk2(s8 * inv, s9 * inv); hi.y = pk2(sa * inv, sb * inv);
        hi.z = pk2(sc * inv, 0.f);      hi.w = 0u;
        *(uint4*)ab       = lo;
        *(uint4*)(ab + 8) = hi;
    }
    __syncthreads();

    // ---- P4: out via MFMA. Per (window=wid, ch-tile ct): D[c][i] = sum_j v[c][j]*att[i][j].
    // K=32 with k>=16 zeroed: B-frag g>=2 lanes set to 0 (A dup is finite -> 0 product).
    // A = vpad rows (b128), B = attb rows (b128). D: col=lane&15=i, row=g*4+reg=ch;
    // stores 13-lane contiguous dword runs, masked col<13 (attb garbage rows n>=13
    // only pollute masked cols). ----
    {
        const int wid  = tid >> 6;           // window 0..7
        const int lane = tid & 63;
        const int col  = lane & 15;
        const int g    = lane >> 4;
        const int gg   = (g & 1) * 8;
        shortx8 bfrag = *(const shortx8*)(&attb[wid * 256 + col * 16 + gg]);
        if (g & 2) bfrag = (shortx8){0, 0, 0, 0, 0, 0, 0, 0};
        const size_t obase = (size_t)(b * 64) * NTOT + v0 + wid * 13 + col;
#pragma unroll
        for (int ct = 0; ct < 4; ++ct) {
            const shortx8 afrag = *(const shortx8*)(&vpad[(ct * 16 + col) * VPS + wid * 16 + gg]);
            floatx4 acc = {0.f, 0.f, 0.f, 0.f};
            acc = __builtin_amdgcn_mfma_f32_16x16x32_bf16(afrag, bfrag, acc, 0, 0, 0);
            if (col < 13) {
                float* op = out + obase + (size_t)(ct * 16 + g * 4) * NTOT;
                op[0]                = acc[0];
                op[(size_t)NTOT]     = acc[1];
                op[(size_t)2 * NTOT] = acc[2];
                op[(size_t)3 * NTOT] = acc[3];
            }
        }
    }
}

extern "C" void kernel_launch(void* const* d_in, const int* in_sizes, int n_in,
                              void* d_out, int out_size, void* d_ws, size_t ws_size,
                              hipStream_t stream) {
    const float* x  = (const float*)d_in[0];
    const float* wq = (const float*)d_in[1];
    const float* bq = (const float*)d_in[2];
    const float* wk = (const float*)d_in[3];
    const float* bk = (const float*)d_in[4];
    const float* wv = (const float*)d_in[5];
    const float* bv = (const float*)d_in[6];
    float* out = (float*)d_out;

    dim3 grid(NTOT / VT, 8);   // 512 tiles x 8 batches = 4096 blocks
    dim3 block(512);
    attn_win13_kernel<<<grid, block, 0, stream>>>(x, wq, bq, wk, bk, wv, bv, out);
}